// Round 3
// baseline (896.435 us; speedup 1.0000x reference)
//
#include <hip/hip_runtime.h>
#include <math.h>

#define TOKS 8192
#define HD 1024
#define ID 2048
#define NE 8

typedef __bf16 bf16_t;
typedef __bf16 bf16x8 __attribute__((ext_vector_type(8)));
typedef float f32x4 __attribute__((ext_vector_type(4)));

// async global->LDS, 16 bytes per lane. LDS dest: wave-uniform base + lane*16.
#define GLOAD(gp, lp)                                                \
  __builtin_amdgcn_global_load_lds(                                  \
      (const __attribute__((address_space(1))) void*)(gp),           \
      (__attribute__((address_space(3))) void*)(lp), 16, 0, 0)

// ---------------- workspace layout (bytes) ----------------
#define WS_COUNTS 0
#define WS_OFFSETS 32
#define WS_CURSOR 64
#define WS_BTOK 128
#define WS_BW (128 + 65536)
#define WS_TE (128 + 2 * 65536)
#define WS_TW (128 + 3 * 65536)
#define WS_WL 263168ull
#define WS_XB 524288ull                       // bf16 x  [8192][1024]  = 16.78 MB
#define WS_H1 (WS_XB + 16777216ull)           // bf16 h1 [16384][2048] = 67.1 MB
#define WS_WT (WS_H1 + 67108864ull)           // bf16 WT (W1T then W2T) = 33.55 MB

#define MAXWL 144
#define BM 256  // m-tile (rows of token bucket)

// ---------------- zero out + counts (hipMemsetAsync is NOT graph-capturable) ----
__global__ void zero_kernel(float* __restrict__ out, int* __restrict__ counts) {
  const int i = (blockIdx.x * 256 + threadIdx.x) * 4;
  *(float4*)(out + i) = make_float4(0.f, 0.f, 0.f, 0.f);
  if (blockIdx.x == 0 && threadIdx.x < NE) counts[threadIdx.x] = 0;
}

// ---------------- x -> bf16 convert: pure streaming, 32B in / 16B out per lane ----
__global__ void convert_kernel(const float* __restrict__ x, bf16_t* __restrict__ xb) {
  const size_t i = ((size_t)blockIdx.x * 256 + threadIdx.x) * 8;
  const float4 a = *(const float4*)(x + i);
  const float4 b = *(const float4*)(x + i + 4);
  bf16_t o[8] = {(bf16_t)a.x, (bf16_t)a.y, (bf16_t)a.z, (bf16_t)a.w,
                 (bf16_t)b.x, (bf16_t)b.y, (bf16_t)b.z, (bf16_t)b.w};
  *(uint4*)(xb + i) = *(uint4*)o;
}

// ---------------- gating: Wg transposed in LDS, coalesced x, 8 tokens/block ----
// Old version: 1-wave blocks, 128 dependent scalar Wg loads/lane -> 205 us at
// 1.9% VALUBusy (pure latency). Now: WgT[8][1024] in LDS (stride-64 reads =
// conflict-free, 2 lanes/bank is free per m136), x read as coalesced dwords.
__global__ __launch_bounds__(256) void gate_kernel(const float* __restrict__ x,
                                                   const float* __restrict__ Wg,
                                                   int* __restrict__ tok_e,
                                                   float* __restrict__ tok_w,
                                                   int* __restrict__ counts) {
  __shared__ float WgT[NE][HD];  // 32 KB
  const int tid = threadIdx.x;
#pragma unroll
  for (int i = 0; i < NE * HD / 256; ++i) {
    const int idx = i * 256 + tid;
    WgT[idx & 7][idx >> 3] = Wg[idx];
  }
  __syncthreads();
  const int wv = tid >> 6;
  const int lane = tid & 63;
#pragma unroll
  for (int s = 0; s < 2; ++s) {
    const int t = blockIdx.x * 8 + wv * 2 + s;
    const float* xrow = x + (size_t)t * HD;
    float acc[NE];
#pragma unroll
    for (int e = 0; e < NE; ++e) acc[e] = 0.f;
#pragma unroll
    for (int i = 0; i < 16; ++i) {
      const int h = i * 64 + lane;
      const float xv = xrow[h];
#pragma unroll
      for (int e = 0; e < NE; ++e) acc[e] += xv * WgT[e][h];
    }
#pragma unroll
    for (int off = 32; off >= 1; off >>= 1) {
#pragma unroll
      for (int e = 0; e < NE; ++e) acc[e] += __shfl_xor(acc[e], off);
    }
    if (lane == 0) {
      int i1 = 0;
      float l1 = acc[0];
#pragma unroll
      for (int e = 1; e < NE; ++e)
        if (acc[e] > l1) { l1 = acc[e]; i1 = e; }
      int i2 = -1;
      float l2 = -3.4e38f;
#pragma unroll
      for (int e = 0; e < NE; ++e)
        if (e != i1 && acc[e] > l2) { l2 = acc[e]; i2 = e; }
      const float q = expf(l2 - l1);
      const float w1 = 1.f / (1.f + q);
      tok_e[2 * t] = i1;
      tok_e[2 * t + 1] = i2;
      tok_w[2 * t] = w1;
      tok_w[2 * t + 1] = q * w1;
      atomicAdd(&counts[i1], 1);
      atomicAdd(&counts[i2], 1);
    }
  }
}

// scan + build dense (expert, m_tile) work-list
__global__ void scan_kernel(const int* __restrict__ counts, int* __restrict__ offsets,
                            int* __restrict__ cursor, int* __restrict__ wl_e,
                            int* __restrict__ wl_m, int* __restrict__ n_work) {
  if (threadIdx.x == 0) {
    int s = 0, idx = 0;
    for (int e = 0; e < NE; ++e) {
      offsets[e] = s;
      cursor[e] = s;
      for (int m = 0; m < counts[e] && idx < MAXWL; m += BM) {
        wl_e[idx] = e;
        wl_m[idx] = m;
        ++idx;
      }
      s += counts[e];
    }
    *n_work = idx;
  }
}

__global__ void scatter_kernel(const int* __restrict__ tok_e, const float* __restrict__ tok_w,
                               int* __restrict__ cursor, int* __restrict__ bucket_tok,
                               float* __restrict__ bucket_w) {
  const int idx = blockIdx.x * 256 + threadIdx.x;
  const int e = tok_e[idx];
  const int pos = atomicAdd(&cursor[e], 1) & (2 * TOKS - 1);
  bucket_tok[pos] = idx >> 1;
  bucket_w[pos] = tok_w[idx];
}

// ---------------- transpose+convert: src [E][K][N] f32 -> dst [E][N][K] bf16 ----
__global__ __launch_bounds__(256) void transpose_convert_kernel(const float* __restrict__ src,
                                                                bf16_t* __restrict__ dst, int K,
                                                                int N) {
  __shared__ float tile[64][65];
  const int e = blockIdx.z;
  const int k0 = blockIdx.x * 64;
  const int n0 = blockIdx.y * 64;
  const float* s = src + (size_t)e * K * N;
  bf16_t* d = dst + (size_t)e * K * N;
  const int t = threadIdx.x;
  const int c = t & 63;
  const int r4 = t >> 6;
#pragma unroll
  for (int p = 0; p < 16; ++p) {
    const int r = p * 4 + r4;
    tile[r][c] = s[(size_t)(k0 + r) * N + n0 + c];
  }
  __syncthreads();
  const int kc = t & 7;
  const int nb = t >> 3;
#pragma unroll
  for (int p = 0; p < 2; ++p) {
    const int n = p * 32 + nb;
    bf16_t o[8];
#pragma unroll
    for (int j = 0; j < 8; ++j) o[j] = (bf16_t)tile[kc * 8 + j][n];
    *(uint4*)(d + (size_t)(n0 + n) * K + k0 + kc * 8) = *(uint4*)o;
  }
}

// ---------------- expert GEMMs: 256x128 block tile ----------------
// Round-1 post-mortem: bottleneck is the per-CU LDS port + staging bytes per
// FLOP, not occupancy and not bank conflicts. 256x128 raises FLOP per
// LDS-read-byte 32 -> 42.7 and halves B-panel staging. 4 waves in 2x2, each
// wave 128x64 output = acc[8][4]; af read per-mt inside the MFMA loop to keep
// VGPR under the 256 cap (__launch_bounds__(256,2) -> 2 blocks/CU).
// Swizzle (both-sides): GLOAD source chunk kch = ((lane&3)^(srow&3))*8, read
// slot = (quad^(lrow&3))*8. LDS tiles [rows][32] bf16.

__global__ __launch_bounds__(256, 2) void gemm1_kernel(
    const bf16_t* __restrict__ xb, const bf16_t* __restrict__ W1T, const float* __restrict__ b1,
    const int* __restrict__ counts, const int* __restrict__ offsets,
    const int* __restrict__ bucket_tok, const int* __restrict__ wl_e,
    const int* __restrict__ wl_m, const int* __restrict__ n_work, bf16_t* __restrict__ h1) {
  const int widx = blockIdx.x;
  if (widx >= *n_work) return;
  const int e = wl_e[widx];
  const int m_base = wl_m[widx];
  const int n_e = counts[e];
  const int n_base = blockIdx.y * 128;
  const int off = offsets[e];

  __shared__ bf16_t As[2][256 * 32];  // 16 KB per buf
  __shared__ bf16_t Bs[2][128 * 32];  // 8 KB per buf

  const int tid = threadIdx.x;
  const int w = tid >> 6;
  const int lane = tid & 63;
  const int quad = lane >> 4;
  const int lrow = lane & 15;
  const int wm = w >> 1;
  const int wn = w & 1;

  const int srow = lane >> 2;
  const int kch = (((lane & 3) ^ (srow & 3)) * 8);
  // A: wave w stages rows w*64 .. w*64+63 (4 GLOADs of 16 rows)
  const bf16_t* ga[4];
#pragma unroll
  for (int g = 0; g < 4; ++g) {
    int r = m_base + w * 64 + g * 16 + srow;
    if (r >= n_e) r = n_e - 1;
    if (r < 0) r = 0;
    ga[g] = xb + (size_t)bucket_tok[off + r] * HD + kch;
  }
  // B: wave w stages rows w*32 .. w*32+31 (2 GLOADs)
  const bf16_t* gb[2];
#pragma unroll
  for (int g = 0; g < 2; ++g)
    gb[g] = W1T + ((size_t)e * ID + n_base + w * 32 + g * 16 + srow) * HD + kch;
  const int laofs = w * 2048 + lane * 8;  // + g*512
  const int lbofs = w * 1024 + lane * 8;  // + g*512

  f32x4 acc[8][4];
#pragma unroll
  for (int mt = 0; mt < 8; ++mt)
#pragma unroll
    for (int nt = 0; nt < 4; ++nt)
#pragma unroll
      for (int r = 0; r < 4; ++r) acc[mt][nt][r] = 0.f;

  // prologue: stage tile 0 into buffer 0
#pragma unroll
  for (int g = 0; g < 4; ++g) GLOAD(ga[g], &As[0][laofs + g * 512]);
#pragma unroll
  for (int g = 0; g < 2; ++g) GLOAD(gb[g], &Bs[0][lbofs + g * 512]);

#define NT1 (HD / 32)
  for (int kt = 0; kt < NT1; ++kt) {
    __syncthreads();  // drains own DMA (tile kt) + guards buffer reuse
    const int cur = kt & 1;
    if (kt + 1 < NT1) {
      const int nxt = cur ^ 1;
      const size_t ko = (size_t)(kt + 1) * 32;
#pragma unroll
      for (int g = 0; g < 4; ++g) GLOAD(ga[g] + ko, &As[nxt][laofs + g * 512]);
#pragma unroll
      for (int g = 0; g < 2; ++g) GLOAD(gb[g] + ko, &Bs[nxt][lbofs + g * 512]);
    }
    const int slot = (quad ^ (lrow & 3)) * 8;
    bf16x8 bfr[4];
#pragma unroll
    for (int i = 0; i < 4; ++i)
      bfr[i] = *(const bf16x8*)(&Bs[cur][(wn * 64 + i * 16 + lrow) * 32 + slot]);
#pragma unroll
    for (int mt = 0; mt < 8; ++mt) {
      const bf16x8 af = *(const bf16x8*)(&As[cur][(wm * 128 + mt * 16 + lrow) * 32 + slot]);
#pragma unroll
      for (int nt = 0; nt < 4; ++nt)
        acc[mt][nt] = __builtin_amdgcn_mfma_f32_16x16x32_bf16(af, bfr[nt], acc[mt][nt], 0, 0, 0);
    }
  }

#pragma unroll
  for (int mt = 0; mt < 8; ++mt) {
#pragma unroll
    for (int r = 0; r < 4; ++r) {
      const int gm = m_base + wm * 128 + mt * 16 + quad * 4 + r;
      if (gm < n_e) {
        bf16_t* orow = h1 + (size_t)(off + gm) * ID;
#pragma unroll
        for (int nt = 0; nt < 4; ++nt) {
          const int gi = n_base + wn * 64 + nt * 16 + lrow;
          float v = acc[mt][nt][r] + b1[e * ID + gi];
          v = 0.5f * v * (1.f + erff(v * 0.70710678118654752f));  // exact-erf GELU
          orow[gi] = (bf16_t)v;
        }
      }
    }
  }
}

__global__ __launch_bounds__(256, 2) void gemm2_kernel(
    const bf16_t* __restrict__ h1, const bf16_t* __restrict__ W2T, const float* __restrict__ b2,
    const int* __restrict__ counts, const int* __restrict__ offsets,
    const int* __restrict__ bucket_tok, const float* __restrict__ bucket_w,
    const int* __restrict__ wl_e, const int* __restrict__ wl_m, const int* __restrict__ n_work,
    float* __restrict__ out) {
  const int widx = blockIdx.x;
  if (widx >= *n_work) return;
  const int e = wl_e[widx];
  const int m_base = wl_m[widx];
  const int n_e = counts[e];
  const int n_base = blockIdx.y * 128;
  const int split = blockIdx.z;  // split-K: 2 x 1024 (keeps grid deep at N=1024)
  const int kbase = split * (ID / 2);
  const int off = offsets[e];

  __shared__ bf16_t As[2][256 * 32];
  __shared__ bf16_t Bs[2][128 * 32];

  const int tid = threadIdx.x;
  const int w = tid >> 6;
  const int lane = tid & 63;
  const int quad = lane >> 4;
  const int lrow = lane & 15;
  const int wm = w >> 1;
  const int wn = w & 1;

  const int srow = lane >> 2;
  const int kch = (((lane & 3) ^ (srow & 3)) * 8);
  const bf16_t* ga[4];
#pragma unroll
  for (int g = 0; g < 4; ++g) {
    int r = m_base + w * 64 + g * 16 + srow;
    if (r >= n_e) r = n_e - 1;
    if (r < 0) r = 0;
    ga[g] = h1 + (size_t)(off + r) * ID + kbase + kch;
  }
  const bf16_t* gb[2];
#pragma unroll
  for (int g = 0; g < 2; ++g)
    gb[g] = W2T + ((size_t)e * HD + n_base + w * 32 + g * 16 + srow) * ID + kbase + kch;
  const int laofs = w * 2048 + lane * 8;
  const int lbofs = w * 1024 + lane * 8;

  f32x4 acc[8][4];
#pragma unroll
  for (int mt = 0; mt < 8; ++mt)
#pragma unroll
    for (int nt = 0; nt < 4; ++nt)
#pragma unroll
      for (int r = 0; r < 4; ++r) acc[mt][nt][r] = 0.f;

#pragma unroll
  for (int g = 0; g < 4; ++g) GLOAD(ga[g], &As[0][laofs + g * 512]);
#pragma unroll
  for (int g = 0; g < 2; ++g) GLOAD(gb[g], &Bs[0][lbofs + g * 512]);

#define NT2 (ID / 2 / 32)
  for (int kt = 0; kt < NT2; ++kt) {
    __syncthreads();
    const int cur = kt & 1;
    if (kt + 1 < NT2) {
      const int nxt = cur ^ 1;
      const size_t ko = (size_t)(kt + 1) * 32;
#pragma unroll
      for (int g = 0; g < 4; ++g) GLOAD(ga[g] + ko, &As[nxt][laofs + g * 512]);
#pragma unroll
      for (int g = 0; g < 2; ++g) GLOAD(gb[g] + ko, &Bs[nxt][lbofs + g * 512]);
    }
    const int slot = (quad ^ (lrow & 3)) * 8;
    bf16x8 bfr[4];
#pragma unroll
    for (int i = 0; i < 4; ++i)
      bfr[i] = *(const bf16x8*)(&Bs[cur][(wn * 64 + i * 16 + lrow) * 32 + slot]);
#pragma unroll
    for (int mt = 0; mt < 8; ++mt) {
      const bf16x8 af = *(const bf16x8*)(&As[cur][(wm * 128 + mt * 16 + lrow) * 32 + slot]);
#pragma unroll
      for (int nt = 0; nt < 4; ++nt)
        acc[mt][nt] = __builtin_amdgcn_mfma_f32_16x16x32_bf16(af, bfr[nt], acc[mt][nt], 0, 0, 0);
    }
  }

#pragma unroll
  for (int mt = 0; mt < 8; ++mt) {
#pragma unroll
    for (int r = 0; r < 4; ++r) {
      const int gm = m_base + wm * 128 + mt * 16 + quad * 4 + r;
      if (gm < n_e) {
        const int pos = off + gm;
        const int tokid = bucket_tok[pos];
        const float wgt = bucket_w[pos];
        float* orow = out + (size_t)tokid * HD;
#pragma unroll
        for (int nt = 0; nt < 4; ++nt) {
          const int gh = n_base + wn * 64 + nt * 16 + lrow;
          float v = acc[mt][nt][r];
          if (split == 0) v += b2[e * HD + gh];  // bias once
          atomicAdd(orow + gh, wgt * v);
        }
      }
    }
  }
}

extern "C" void kernel_launch(void* const* d_in, const int* in_sizes, int n_in,
                              void* d_out, int out_size, void* d_ws, size_t ws_size,
                              hipStream_t stream) {
  const float* x = (const float*)d_in[0];
  const float* Wg = (const float*)d_in[1];
  const float* W1 = (const float*)d_in[2];
  const float* b1 = (const float*)d_in[3];
  const float* W2 = (const float*)d_in[4];
  const float* b2 = (const float*)d_in[5];
  float* out = (float*)d_out;
  char* ws = (char*)d_ws;

  int* counts = (int*)(ws + WS_COUNTS);
  int* offsets = (int*)(ws + WS_OFFSETS);
  int* cursor = (int*)(ws + WS_CURSOR);
  int* bucket_tok = (int*)(ws + WS_BTOK);
  float* bucket_w = (float*)(ws + WS_BW);
  int* tok_e = (int*)(ws + WS_TE);
  float* tok_w = (float*)(ws + WS_TW);
  int* wl_e = (int*)(ws + WS_WL);
  int* wl_m = wl_e + MAXWL;
  int* n_work = wl_m + MAXWL;
  bf16_t* xb = (bf16_t*)(ws + WS_XB);
  bf16_t* h1 = (bf16_t*)(ws + WS_H1);
  bf16_t* WT = (bf16_t*)(ws + WS_WT);

  zero_kernel<<<(TOKS * HD / 4) / 256, 256, 0, stream>>>(out, counts);
  convert_kernel<<<TOKS * HD / (256 * 8), 256, 0, stream>>>(x, xb);
  gate_kernel<<<TOKS / 8, 256, 0, stream>>>(x, Wg, tok_e, tok_w, counts);
  scan_kernel<<<1, 64, 0, stream>>>(counts, offsets, cursor, wl_e, wl_m, n_work);
  scatter_kernel<<<TOKS * 2 / 256, 256, 0, stream>>>(tok_e, tok_w, cursor, bucket_tok, bucket_w);
  transpose_convert_kernel<<<dim3(HD / 64, ID / 64, NE), 256, 0, stream>>>(W1, WT, HD, ID);
  gemm1_kernel<<<dim3(MAXWL, ID / 128), 256, 0, stream>>>(xb, WT, b1, counts, offsets, bucket_tok,
                                                          wl_e, wl_m, n_work, h1);
  transpose_convert_kernel<<<dim3(ID / 64, HD / 64, NE), 256, 0, stream>>>(W2, WT, ID, HD);
  gemm2_kernel<<<dim3(MAXWL, HD / 128, 2), 256, 0, stream>>>(h1, WT, b2, counts, offsets,
                                                             bucket_tok, bucket_w, wl_e, wl_m,
                                                             n_work, out);
}

// Round 4
// 777.613 us; speedup vs baseline: 1.1528x; 1.1528x over previous
//
#include <hip/hip_runtime.h>
#include <math.h>

#define TOKS 8192
#define HD 1024
#define ID 2048
#define NE 8

typedef __bf16 bf16_t;
typedef __bf16 bf16x8 __attribute__((ext_vector_type(8)));
typedef float f32x4 __attribute__((ext_vector_type(4)));

// async global->LDS, 16 bytes per lane. LDS dest: wave-uniform base + lane*16.
#define GLOAD(gp, lp)                                                \
  __builtin_amdgcn_global_load_lds(                                  \
      (const __attribute__((address_space(1))) void*)(gp),           \
      (__attribute__((address_space(3))) void*)(lp), 16, 0, 0)

#define WAITV(N) asm volatile("s_waitcnt vmcnt(" #N ")" ::: "memory")
#define WAITL0() asm volatile("s_waitcnt lgkmcnt(0)" ::: "memory")

// ---------------- workspace layout (bytes) ----------------
#define WS_COUNTS 0
#define WS_OFFSETS 32
#define WS_CURSOR 64
#define WS_BTOK 128
#define WS_BW (128 + 65536)
#define WS_TE (128 + 2 * 65536)
#define WS_TW (128 + 3 * 65536)
#define WS_WL 263168ull
#define WS_XB 524288ull                       // bf16 x  [8192][1024]  = 16.78 MB
#define WS_H1 (WS_XB + 16777216ull)           // bf16 h1 [16384][2048] = 67.1 MB
#define WS_WT (WS_H1 + 67108864ull)           // bf16 WT (W1T then W2T) = 33.55 MB

#define MAXWL 144
#define BM 128  // m-tile (rows of token bucket) — 256x128 regressed (r3), back to 128^2

// ---------------- zero out + counts (hipMemsetAsync is NOT graph-capturable) ----
__global__ void zero_kernel(float* __restrict__ out, int* __restrict__ counts) {
  const int i = (blockIdx.x * 256 + threadIdx.x) * 4;
  *(float4*)(out + i) = make_float4(0.f, 0.f, 0.f, 0.f);
  if (blockIdx.x == 0 && threadIdx.x < NE) counts[threadIdx.x] = 0;
}

// ---------------- x -> bf16 convert: pure streaming, 32B in / 16B out per lane ----
__global__ void convert_kernel(const float* __restrict__ x, bf16_t* __restrict__ xb) {
  const size_t i = ((size_t)blockIdx.x * 256 + threadIdx.x) * 8;
  const float4 a = *(const float4*)(x + i);
  const float4 b = *(const float4*)(x + i + 4);
  bf16_t o[8] = {(bf16_t)a.x, (bf16_t)a.y, (bf16_t)a.z, (bf16_t)a.w,
                 (bf16_t)b.x, (bf16_t)b.y, (bf16_t)b.z, (bf16_t)b.w};
  *(uint4*)(xb + i) = *(uint4*)o;
}

// ---------------- gating: Wg transposed in LDS, coalesced x, 8 tokens/block ----
// (verified round 3: gate dropped out of top-5; was 205 us as 1-wave latency-bound)
__global__ __launch_bounds__(256) void gate_kernel(const float* __restrict__ x,
                                                   const float* __restrict__ Wg,
                                                   int* __restrict__ tok_e,
                                                   float* __restrict__ tok_w,
                                                   int* __restrict__ counts) {
  __shared__ float WgT[NE][HD];  // 32 KB
  const int tid = threadIdx.x;
#pragma unroll
  for (int i = 0; i < NE * HD / 256; ++i) {
    const int idx = i * 256 + tid;
    WgT[idx & 7][idx >> 3] = Wg[idx];
  }
  __syncthreads();
  const int wv = tid >> 6;
  const int lane = tid & 63;
#pragma unroll
  for (int s = 0; s < 2; ++s) {
    const int t = blockIdx.x * 8 + wv * 2 + s;
    const float* xrow = x + (size_t)t * HD;
    float acc[NE];
#pragma unroll
    for (int e = 0; e < NE; ++e) acc[e] = 0.f;
#pragma unroll
    for (int i = 0; i < 16; ++i) {
      const int h = i * 64 + lane;
      const float xv = xrow[h];
#pragma unroll
      for (int e = 0; e < NE; ++e) acc[e] += xv * WgT[e][h];
    }
#pragma unroll
    for (int off = 32; off >= 1; off >>= 1) {
#pragma unroll
      for (int e = 0; e < NE; ++e) acc[e] += __shfl_xor(acc[e], off);
    }
    if (lane == 0) {
      int i1 = 0;
      float l1 = acc[0];
#pragma unroll
      for (int e = 1; e < NE; ++e)
        if (acc[e] > l1) { l1 = acc[e]; i1 = e; }
      int i2 = -1;
      float l2 = -3.4e38f;
#pragma unroll
      for (int e = 0; e < NE; ++e)
        if (e != i1 && acc[e] > l2) { l2 = acc[e]; i2 = e; }
      const float q = expf(l2 - l1);
      const float w1 = 1.f / (1.f + q);
      tok_e[2 * t] = i1;
      tok_e[2 * t + 1] = i2;
      tok_w[2 * t] = w1;
      tok_w[2 * t + 1] = q * w1;
      atomicAdd(&counts[i1], 1);
      atomicAdd(&counts[i2], 1);
    }
  }
}

// scan + build dense (expert, m_tile) work-list
__global__ void scan_kernel(const int* __restrict__ counts, int* __restrict__ offsets,
                            int* __restrict__ cursor, int* __restrict__ wl_e,
                            int* __restrict__ wl_m, int* __restrict__ n_work) {
  if (threadIdx.x == 0) {
    int s = 0, idx = 0;
    for (int e = 0; e < NE; ++e) {
      offsets[e] = s;
      cursor[e] = s;
      for (int m = 0; m < counts[e] && idx < MAXWL; m += BM) {
        wl_e[idx] = e;
        wl_m[idx] = m;
        ++idx;
      }
      s += counts[e];
    }
    *n_work = idx;
  }
}

__global__ void scatter_kernel(const int* __restrict__ tok_e, const float* __restrict__ tok_w,
                               int* __restrict__ cursor, int* __restrict__ bucket_tok,
                               float* __restrict__ bucket_w) {
  const int idx = blockIdx.x * 256 + threadIdx.x;
  const int e = tok_e[idx];
  const int pos = atomicAdd(&cursor[e], 1) & (2 * TOKS - 1);
  bucket_tok[pos] = idx >> 1;
  bucket_w[pos] = tok_w[idx];
}

// ---------------- transpose+convert: src [E][K][N] f32 -> dst [E][N][K] bf16 ----
__global__ __launch_bounds__(256) void transpose_convert_kernel(const float* __restrict__ src,
                                                                bf16_t* __restrict__ dst, int K,
                                                                int N) {
  __shared__ float tile[64][65];
  const int e = blockIdx.z;
  const int k0 = blockIdx.x * 64;
  const int n0 = blockIdx.y * 64;
  const float* s = src + (size_t)e * K * N;
  bf16_t* d = dst + (size_t)e * K * N;
  const int t = threadIdx.x;
  const int c = t & 63;
  const int r4 = t >> 6;
#pragma unroll
  for (int p = 0; p < 16; ++p) {
    const int r = p * 4 + r4;
    tile[r][c] = s[(size_t)(k0 + r) * N + n0 + c];
  }
  __syncthreads();
  const int kc = t & 7;
  const int nb = t >> 3;
#pragma unroll
  for (int p = 0; p < 2; ++p) {
    const int n = p * 32 + nb;
    bf16_t o[8];
#pragma unroll
    for (int j = 0; j < 8; ++j) o[j] = (bf16_t)tile[kc * 8 + j][n];
    *(uint4*)(d + (size_t)(n0 + n) * K + k0 + kc * 8) = *(uint4*)o;
  }
}

// ---------------- expert GEMMs: 128x128 tile, 3-buffer counted-vmcnt pipeline ----
// Rounds 0-3 showed: 2-phase loops here sit at 260-340 TF with ALL pipes idle
// (MfmaUtil<=14, VALU<=12, HBM<=31%, conflicts immaterial) regardless of tile.
// Diagnosis: per-iteration vmcnt(0) drain at the barrier waits ~900cy HBM
// latency of the prefetch issued the SAME iteration (only 16 MFMA of cover).
// Fix (AITER-style counted waits): 3 LDS buffers; iter kt issues tile kt+2,
// waits vmcnt(8) (tile kt landed; kt+1/kt+2 stay in flight -> load-to-use
// distance = 2 iterations), raw s_barrier x2/iter, sched_barrier fence (rule
// #18). LDS 3x16KB=48KB -> 3 blocks/CU (launch_bounds(256,3)).
// Race audit: buf (kt+2)%3 == (kt-1)%3; its readers (iter kt-1) drain lgkm
// before barrier #1 of iter kt, which precedes the overwriting GLOADs.
// Tile-kt visibility: per-wave vmcnt wait + barrier #2 before any ds_read.
// Swizzle (both-sides, rule #21): GLOAD source chunk kch=((lane&3)^(srow&3))*8,
// read slot (quad^(lrow&3))*8. n_work excludes empty experts -> n_e >= 1.

__global__ __launch_bounds__(256, 3) void gemm1_kernel(
    const bf16_t* __restrict__ xb, const bf16_t* __restrict__ W1T, const float* __restrict__ b1,
    const int* __restrict__ counts, const int* __restrict__ offsets,
    const int* __restrict__ bucket_tok, const int* __restrict__ wl_e,
    const int* __restrict__ wl_m, const int* __restrict__ n_work, bf16_t* __restrict__ h1) {
  const int widx = blockIdx.x;
  if (widx >= *n_work) return;
  const int e = wl_e[widx];
  const int m_base = wl_m[widx];
  const int n_e = counts[e];
  const int n_base = blockIdx.y * 128;
  const int off = offsets[e];

  __shared__ bf16_t As[3][128 * 32];  // 8 KB each
  __shared__ bf16_t Bs[3][128 * 32];

  const int tid = threadIdx.x;
  const int w = tid >> 6;
  const int lane = tid & 63;
  const int quad = lane >> 4;
  const int lrow = lane & 15;
  const int wm = w >> 1;   // 64-row half
  const int wn = w & 1;    // 64-col half

  const int srow = lane >> 2;                       // 16 rows per GLOAD
  const int kch = (((lane & 3) ^ (srow & 3)) * 8);  // pre-swizzled source chunk
  int r0 = m_base + w * 32 + srow;
  int r1 = r0 + 16;
  if (r0 >= n_e) r0 = n_e - 1;
  if (r1 >= n_e) r1 = n_e - 1;
  const bf16_t* ga0 = xb + (size_t)bucket_tok[off + r0] * HD + kch;
  const bf16_t* ga1 = xb + (size_t)bucket_tok[off + r1] * HD + kch;
  const bf16_t* gb0 = W1T + ((size_t)e * ID + n_base + w * 32 + srow) * HD + kch;
  const bf16_t* gb1 = gb0 + (size_t)16 * HD;
  const int laofs0 = w * 1024 + lane * 8;  // rows w*32.. in [128][32]
  const int laofs1 = laofs0 + 512;         // +16 rows

  f32x4 acc[4][4];
#pragma unroll
  for (int mt = 0; mt < 4; ++mt)
#pragma unroll
    for (int nt = 0; nt < 4; ++nt)
#pragma unroll
      for (int r = 0; r < 4; ++r) acc[mt][nt][r] = 0.f;

  // prologue: stage tiles 0 and 1 (8 outstanding GLOADs/wave)
#pragma unroll
  for (int p = 0; p < 2; ++p) {
    const size_t ko = (size_t)p * 32;
    GLOAD(ga0 + ko, &As[p][laofs0]);
    GLOAD(ga1 + ko, &As[p][laofs1]);
    GLOAD(gb0 + ko, &Bs[p][laofs0]);
    GLOAD(gb1 + ko, &Bs[p][laofs1]);
  }

#define NT1 (HD / 32)
  for (int kt = 0; kt < NT1; ++kt) {
    WAITL0();                          // prior iter's ds_reads done (per-wave)
    __builtin_amdgcn_s_barrier();      // #1: buf[(kt+2)%3] free to overwrite
    if (kt + 2 < NT1) {
      const int nxt = (kt + 2) % 3;
      const size_t ko = (size_t)(kt + 2) * 32;
      GLOAD(ga0 + ko, &As[nxt][laofs0]);
      GLOAD(ga1 + ko, &As[nxt][laofs1]);
      GLOAD(gb0 + ko, &Bs[nxt][laofs0]);
      GLOAD(gb1 + ko, &Bs[nxt][laofs1]);
      WAITV(8);                        // tile kt landed; kt+1,kt+2 in flight
    } else if (kt + 1 < NT1) {
      WAITV(4);
    } else {
      WAITV(0);
    }
    __builtin_amdgcn_s_barrier();      // #2: tile kt visible to all waves
    __builtin_amdgcn_sched_barrier(0); // fence: no ds_read hoists above
    const int cur = kt % 3;
    const int slot = (quad ^ (lrow & 3)) * 8;
    bf16x8 af[4], bfr[4];
#pragma unroll
    for (int i = 0; i < 4; ++i) {
      af[i] = *(const bf16x8*)(&As[cur][(wm * 64 + i * 16 + lrow) * 32 + slot]);
      bfr[i] = *(const bf16x8*)(&Bs[cur][(wn * 64 + i * 16 + lrow) * 32 + slot]);
    }
#pragma unroll
    for (int mt = 0; mt < 4; ++mt)
#pragma unroll
      for (int nt = 0; nt < 4; ++nt)
        acc[mt][nt] =
            __builtin_amdgcn_mfma_f32_16x16x32_bf16(af[mt], bfr[nt], acc[mt][nt], 0, 0, 0);
  }

#pragma unroll
  for (int mt = 0; mt < 4; ++mt) {
#pragma unroll
    for (int r = 0; r < 4; ++r) {
      const int gm = m_base + wm * 64 + mt * 16 + quad * 4 + r;
      if (gm < n_e) {
        bf16_t* orow = h1 + (size_t)(off + gm) * ID;
#pragma unroll
        for (int nt = 0; nt < 4; ++nt) {
          const int gi = n_base + wn * 64 + nt * 16 + lrow;
          float v = acc[mt][nt][r] + b1[e * ID + gi];
          v = 0.5f * v * (1.f + erff(v * 0.70710678118654752f));  // exact-erf GELU
          orow[gi] = (bf16_t)v;
        }
      }
    }
  }
}

__global__ __launch_bounds__(256, 3) void gemm2_kernel(
    const bf16_t* __restrict__ h1, const bf16_t* __restrict__ W2T, const float* __restrict__ b2,
    const int* __restrict__ counts, const int* __restrict__ offsets,
    const int* __restrict__ bucket_tok, const float* __restrict__ bucket_w,
    const int* __restrict__ wl_e, const int* __restrict__ wl_m, const int* __restrict__ n_work,
    float* __restrict__ out) {
  const int widx = blockIdx.x;
  if (widx >= *n_work) return;
  const int e = wl_e[widx];
  const int m_base = wl_m[widx];
  const int n_e = counts[e];
  const int n_base = blockIdx.y * 128;
  const int off = offsets[e];

  __shared__ bf16_t As[3][128 * 32];
  __shared__ bf16_t Bs[3][128 * 32];

  const int tid = threadIdx.x;
  const int w = tid >> 6;
  const int lane = tid & 63;
  const int quad = lane >> 4;
  const int lrow = lane & 15;
  const int wm = w >> 1;
  const int wn = w & 1;

  const int srow = lane >> 2;
  const int kch = (((lane & 3) ^ (srow & 3)) * 8);
  int r0 = m_base + w * 32 + srow;
  int r1 = r0 + 16;
  if (r0 >= n_e) r0 = n_e - 1;
  if (r1 >= n_e) r1 = n_e - 1;
  const bf16_t* ga0 = h1 + (size_t)(off + r0) * ID + kch;
  const bf16_t* ga1 = h1 + (size_t)(off + r1) * ID + kch;
  const bf16_t* gb0 = W2T + ((size_t)e * HD + n_base + w * 32 + srow) * ID + kch;
  const bf16_t* gb1 = gb0 + (size_t)16 * ID;
  const int laofs0 = w * 1024 + lane * 8;
  const int laofs1 = laofs0 + 512;

  f32x4 acc[4][4];
#pragma unroll
  for (int mt = 0; mt < 4; ++mt)
#pragma unroll
    for (int nt = 0; nt < 4; ++nt)
#pragma unroll
      for (int r = 0; r < 4; ++r) acc[mt][nt][r] = 0.f;

#pragma unroll
  for (int p = 0; p < 2; ++p) {
    const size_t ko = (size_t)p * 32;
    GLOAD(ga0 + ko, &As[p][laofs0]);
    GLOAD(ga1 + ko, &As[p][laofs1]);
    GLOAD(gb0 + ko, &Bs[p][laofs0]);
    GLOAD(gb1 + ko, &Bs[p][laofs1]);
  }

#define NT2 (ID / 32)
  for (int kt = 0; kt < NT2; ++kt) {
    WAITL0();
    __builtin_amdgcn_s_barrier();
    if (kt + 2 < NT2) {
      const int nxt = (kt + 2) % 3;
      const size_t ko = (size_t)(kt + 2) * 32;
      GLOAD(ga0 + ko, &As[nxt][laofs0]);
      GLOAD(ga1 + ko, &As[nxt][laofs1]);
      GLOAD(gb0 + ko, &Bs[nxt][laofs0]);
      GLOAD(gb1 + ko, &Bs[nxt][laofs1]);
      WAITV(8);
    } else if (kt + 1 < NT2) {
      WAITV(4);
    } else {
      WAITV(0);
    }
    __builtin_amdgcn_s_barrier();
    __builtin_amdgcn_sched_barrier(0);
    const int cur = kt % 3;
    const int slot = (quad ^ (lrow & 3)) * 8;
    bf16x8 af[4], bfr[4];
#pragma unroll
    for (int i = 0; i < 4; ++i) {
      af[i] = *(const bf16x8*)(&As[cur][(wm * 64 + i * 16 + lrow) * 32 + slot]);
      bfr[i] = *(const bf16x8*)(&Bs[cur][(wn * 64 + i * 16 + lrow) * 32 + slot]);
    }
#pragma unroll
    for (int mt = 0; mt < 4; ++mt)
#pragma unroll
      for (int nt = 0; nt < 4; ++nt)
        acc[mt][nt] =
            __builtin_amdgcn_mfma_f32_16x16x32_bf16(af[mt], bfr[nt], acc[mt][nt], 0, 0, 0);
  }

#pragma unroll
  for (int mt = 0; mt < 4; ++mt) {
#pragma unroll
    for (int r = 0; r < 4; ++r) {
      const int gm = m_base + wm * 64 + mt * 16 + quad * 4 + r;
      if (gm < n_e) {
        const int pos = off + gm;
        const int tokid = bucket_tok[pos];
        const float wgt = bucket_w[pos];
        float* orow = out + (size_t)tokid * HD;
#pragma unroll
        for (int nt = 0; nt < 4; ++nt) {
          const int gh = n_base + wn * 64 + nt * 16 + lrow;
          float v = acc[mt][nt][r] + b2[e * HD + gh];
          atomicAdd(orow + gh, wgt * v);
        }
      }
    }
  }
}

extern "C" void kernel_launch(void* const* d_in, const int* in_sizes, int n_in,
                              void* d_out, int out_size, void* d_ws, size_t ws_size,
                              hipStream_t stream) {
  const float* x = (const float*)d_in[0];
  const float* Wg = (const float*)d_in[1];
  const float* W1 = (const float*)d_in[2];
  const float* b1 = (const float*)d_in[3];
  const float* W2 = (const float*)d_in[4];
  const float* b2 = (const float*)d_in[5];
  float* out = (float*)d_out;
  char* ws = (char*)d_ws;

  int* counts = (int*)(ws + WS_COUNTS);
  int* offsets = (int*)(ws + WS_OFFSETS);
  int* cursor = (int*)(ws + WS_CURSOR);
  int* bucket_tok = (int*)(ws + WS_BTOK);
  float* bucket_w = (float*)(ws + WS_BW);
  int* tok_e = (int*)(ws + WS_TE);
  float* tok_w = (float*)(ws + WS_TW);
  int* wl_e = (int*)(ws + WS_WL);
  int* wl_m = wl_e + MAXWL;
  int* n_work = wl_m + MAXWL;
  bf16_t* xb = (bf16_t*)(ws + WS_XB);
  bf16_t* h1 = (bf16_t*)(ws + WS_H1);
  bf16_t* WT = (bf16_t*)(ws + WS_WT);

  zero_kernel<<<(TOKS * HD / 4) / 256, 256, 0, stream>>>(out, counts);
  convert_kernel<<<TOKS * HD / (256 * 8), 256, 0, stream>>>(x, xb);
  gate_kernel<<<TOKS / 8, 256, 0, stream>>>(x, Wg, tok_e, tok_w, counts);
  scan_kernel<<<1, 64, 0, stream>>>(counts, offsets, cursor, wl_e, wl_m, n_work);
  scatter_kernel<<<TOKS * 2 / 256, 256, 0, stream>>>(tok_e, tok_w, cursor, bucket_tok, bucket_w);
  transpose_convert_kernel<<<dim3(HD / 64, ID / 64, NE), 256, 0, stream>>>(W1, WT, HD, ID);
  gemm1_kernel<<<dim3(MAXWL, ID / 128), 256, 0, stream>>>(xb, WT, b1, counts, offsets, bucket_tok,
                                                          wl_e, wl_m, n_work, h1);
  transpose_convert_kernel<<<dim3(ID / 64, HD / 64, NE), 256, 0, stream>>>(W2, WT, ID, HD);
  gemm2_kernel<<<dim3(MAXWL, HD / 128), 256, 0, stream>>>(h1, WT, b2, counts, offsets,
                                                          bucket_tok, bucket_w, wl_e, wl_m,
                                                          n_work, out);
}

// Round 5
// 542.381 us; speedup vs baseline: 1.6528x; 1.4337x over previous
//
#include <hip/hip_runtime.h>
#include <math.h>

#define TOKS 8192
#define HD 1024
#define ID 2048
#define NE 8

typedef __bf16 bf16_t;
typedef __bf16 bf16x8 __attribute__((ext_vector_type(8)));
typedef float f32x4 __attribute__((ext_vector_type(4)));

// async global->LDS, 16 bytes per lane. LDS dest: wave-uniform base + lane*16.
#define GLOAD(gp, lp)                                                \
  __builtin_amdgcn_global_load_lds(                                  \
      (const __attribute__((address_space(1))) void*)(gp),           \
      (__attribute__((address_space(3))) void*)(lp), 16, 0, 0)

#define WAITV(N) asm volatile("s_waitcnt vmcnt(" #N ")" ::: "memory")
#define WAITL0() asm volatile("s_waitcnt lgkmcnt(0)" ::: "memory")

// ---------------- workspace layout (bytes) ----------------
#define WS_COUNTS 0
#define WS_OFFSETS 32
#define WS_BTOK 128
#define WS_BW (128 + 65536)
#define WS_TE (128 + 2 * 65536)
#define WS_TW (128 + 3 * 65536)
#define WS_WL 263168ull
#define WS_BLKC 266240ull                     // blk_cnt  [64][8] int
#define WS_BLKB 270336ull                     // blk_base [64][8] int
#define WS_XB 524288ull                       // bf16 x  [8192][1024]  = 16.78 MB
#define WS_H1 (WS_XB + 16777216ull)           // bf16 h1 [16384][2048] = 67.1 MB
#define WS_WT (WS_H1 + 67108864ull)           // bf16 WT (W1T then W2T) = 33.55 MB

#define MAXWL 144
#define BM 128  // m-tile (rows of token bucket)

// ---------------- zero out (hipMemsetAsync is NOT graph-capturable) ----
__global__ void zero_kernel(float* __restrict__ out) {
  const int i = (blockIdx.x * 256 + threadIdx.x) * 4;
  *(float4*)(out + i) = make_float4(0.f, 0.f, 0.f, 0.f);
}

// ---------------- x -> bf16 convert: pure streaming, 32B in / 16B out per lane ----
__global__ void convert_kernel(const float* __restrict__ x, bf16_t* __restrict__ xb) {
  const size_t i = ((size_t)blockIdx.x * 256 + threadIdx.x) * 8;
  const float4 a = *(const float4*)(x + i);
  const float4 b = *(const float4*)(x + i + 4);
  bf16_t o[8] = {(bf16_t)a.x, (bf16_t)a.y, (bf16_t)a.z, (bf16_t)a.w,
                 (bf16_t)b.x, (bf16_t)b.y, (bf16_t)b.z, (bf16_t)b.w};
  *(uint4*)(xb + i) = *(uint4*)o;
}

// ---------------- gating: top-2 + weights. NO ATOMICS (r4 post-mortem: 16384
// same-cache-line atomicAdds serialized in the L2 atomic unit ~= the whole
// 199us dispatch; counts now come from hist/scan ballot counting-sort). ----
__global__ __launch_bounds__(256) void gate_kernel(const float* __restrict__ x,
                                                   const float* __restrict__ Wg,
                                                   int* __restrict__ tok_e,
                                                   float* __restrict__ tok_w) {
  __shared__ float WgT[NE][HD];  // 32 KB
  const int tid = threadIdx.x;
#pragma unroll
  for (int i = 0; i < NE * HD / 256; ++i) {
    const int idx = i * 256 + tid;
    WgT[idx & 7][idx >> 3] = Wg[idx];
  }
  __syncthreads();
  const int wv = tid >> 6;
  const int lane = tid & 63;
#pragma unroll
  for (int s = 0; s < 2; ++s) {
    const int t = blockIdx.x * 8 + wv * 2 + s;
    const float* xrow = x + (size_t)t * HD;
    float acc[NE];
#pragma unroll
    for (int e = 0; e < NE; ++e) acc[e] = 0.f;
#pragma unroll
    for (int i = 0; i < 16; ++i) {
      const int h = i * 64 + lane;
      const float xv = xrow[h];
#pragma unroll
      for (int e = 0; e < NE; ++e) acc[e] += xv * WgT[e][h];
    }
#pragma unroll
    for (int off = 32; off >= 1; off >>= 1) {
#pragma unroll
      for (int e = 0; e < NE; ++e) acc[e] += __shfl_xor(acc[e], off);
    }
    if (lane == 0) {
      int i1 = 0;
      float l1 = acc[0];
#pragma unroll
      for (int e = 1; e < NE; ++e)
        if (acc[e] > l1) { l1 = acc[e]; i1 = e; }
      int i2 = -1;
      float l2 = -3.4e38f;
#pragma unroll
      for (int e = 0; e < NE; ++e)
        if (e != i1 && acc[e] > l2) { l2 = acc[e]; i2 = e; }
      const float q = expf(l2 - l1);
      const float w1 = 1.f / (1.f + q);
      tok_e[2 * t] = i1;
      tok_e[2 * t + 1] = i2;
      tok_w[2 * t] = w1;
      tok_w[2 * t + 1] = q * w1;
    }
  }
}

// ---------------- histogram: per-block per-expert counts via wave ballots ----
__global__ __launch_bounds__(256) void hist_kernel(const int* __restrict__ tok_e,
                                                   int* __restrict__ blk_cnt) {
  __shared__ int wcnt[4][NE];
  const int tid = threadIdx.x;
  const int idx = blockIdx.x * 256 + tid;
  const int e = tok_e[idx];
  const int w = tid >> 6;
  const int lane = tid & 63;
#pragma unroll
  for (int e0 = 0; e0 < NE; ++e0) {
    const unsigned long long m = __ballot(e == e0);
    if (lane == 0) wcnt[w][e0] = __popcll(m);
  }
  __syncthreads();
  if (tid < NE)
    blk_cnt[blockIdx.x * NE + tid] =
        wcnt[0][tid] + wcnt[1][tid] + wcnt[2][tid] + wcnt[3][tid];
}

// ---------------- scan: one wave; 64-wide shfl prefix-sum per expert ----
__global__ void scan_kernel(const int* __restrict__ blk_cnt, int* __restrict__ counts,
                            int* __restrict__ offsets, int* __restrict__ blk_base,
                            int* __restrict__ wl_e, int* __restrict__ wl_m,
                            int* __restrict__ n_work) {
  const int b = threadIdx.x;  // 0..63, one per scatter block
  int c[NE], pre[NE], tot[NE];
#pragma unroll
  for (int e = 0; e < NE; ++e) c[e] = blk_cnt[b * NE + e];
#pragma unroll
  for (int e = 0; e < NE; ++e) {
    int v = c[e];
#pragma unroll
    for (int off = 1; off < 64; off <<= 1) {
      const int u = __shfl_up(v, off);
      if (b >= off) v += u;
    }
    pre[e] = v - c[e];          // exclusive prefix over blocks
    tot[e] = __shfl(v, 63);     // expert total
  }
  int off_[NE];
  int s = 0;
#pragma unroll
  for (int e = 0; e < NE; ++e) {
    off_[e] = s;
    s += tot[e];
  }
#pragma unroll
  for (int e = 0; e < NE; ++e) blk_base[b * NE + e] = off_[e] + pre[e];
  if (b == 0) {
    int idx = 0;
    for (int e = 0; e < NE; ++e) {
      counts[e] = tot[e];
      offsets[e] = off_[e];
      for (int m = 0; m < tot[e] && idx < MAXWL; m += BM) {
        wl_e[idx] = e;
        wl_m[idx] = m;
        ++idx;
      }
    }
    *n_work = idx;
  }
}

// ---------------- scatter: position = blk_base + wave prefix + ballot rank ----
__global__ __launch_bounds__(256) void scatter_kernel(const int* __restrict__ tok_e,
                                                      const float* __restrict__ tok_w,
                                                      const int* __restrict__ blk_base,
                                                      int* __restrict__ bucket_tok,
                                                      float* __restrict__ bucket_w) {
  __shared__ int wcnt[4][NE];
  const int tid = threadIdx.x;
  const int idx = blockIdx.x * 256 + tid;
  const int e = tok_e[idx];
  const int w = tid >> 6;
  const int lane = tid & 63;
  unsigned long long mym = 0;
#pragma unroll
  for (int e0 = 0; e0 < NE; ++e0) {
    const unsigned long long m = __ballot(e == e0);
    if (lane == 0) wcnt[w][e0] = __popcll(m);
    if (e0 == e) mym = m;
  }
  __syncthreads();
  int base = blk_base[blockIdx.x * NE + e];
  for (int w2 = 0; w2 < w; ++w2) base += wcnt[w2][e];
  const int rank = __popcll(mym & ((1ull << lane) - 1ull));
  const int pos = base + rank;
  bucket_tok[pos] = idx >> 1;
  bucket_w[pos] = tok_w[idx];
}

// ---------------- transpose+convert: src [E][K][N] f32 -> dst [E][N][K] bf16 ----
__global__ __launch_bounds__(256) void transpose_convert_kernel(const float* __restrict__ src,
                                                                bf16_t* __restrict__ dst, int K,
                                                                int N) {
  __shared__ float tile[64][65];
  const int e = blockIdx.z;
  const int k0 = blockIdx.x * 64;
  const int n0 = blockIdx.y * 64;
  const float* s = src + (size_t)e * K * N;
  bf16_t* d = dst + (size_t)e * K * N;
  const int t = threadIdx.x;
  const int c = t & 63;
  const int r4 = t >> 6;
#pragma unroll
  for (int p = 0; p < 16; ++p) {
    const int r = p * 4 + r4;
    tile[r][c] = s[(size_t)(k0 + r) * N + n0 + c];
  }
  __syncthreads();
  const int kc = t & 7;
  const int nb = t >> 3;
#pragma unroll
  for (int p = 0; p < 2; ++p) {
    const int n = p * 32 + nb;
    bf16_t o[8];
#pragma unroll
    for (int j = 0; j < 8; ++j) o[j] = (bf16_t)tile[kc * 8 + j][n];
    *(uint4*)(d + (size_t)(n0 + n) * K + k0 + kc * 8) = *(uint4*)o;
  }
}

// ---------------- expert GEMMs: 128x128 tile, 3-buffer counted-vmcnt pipeline ----
// (verified round 4: passed, gemm2 dropped 262 -> <199 us)

__global__ __launch_bounds__(256, 3) void gemm1_kernel(
    const bf16_t* __restrict__ xb, const bf16_t* __restrict__ W1T, const float* __restrict__ b1,
    const int* __restrict__ counts, const int* __restrict__ offsets,
    const int* __restrict__ bucket_tok, const int* __restrict__ wl_e,
    const int* __restrict__ wl_m, const int* __restrict__ n_work, bf16_t* __restrict__ h1) {
  const int widx = blockIdx.x;
  if (widx >= *n_work) return;
  const int e = wl_e[widx];
  const int m_base = wl_m[widx];
  const int n_e = counts[e];
  const int n_base = blockIdx.y * 128;
  const int off = offsets[e];

  __shared__ bf16_t As[3][128 * 32];  // 8 KB each
  __shared__ bf16_t Bs[3][128 * 32];

  const int tid = threadIdx.x;
  const int w = tid >> 6;
  const int lane = tid & 63;
  const int quad = lane >> 4;
  const int lrow = lane & 15;
  const int wm = w >> 1;   // 64-row half
  const int wn = w & 1;    // 64-col half

  const int srow = lane >> 2;                       // 16 rows per GLOAD
  const int kch = (((lane & 3) ^ (srow & 3)) * 8);  // pre-swizzled source chunk
  int r0 = m_base + w * 32 + srow;
  int r1 = r0 + 16;
  if (r0 >= n_e) r0 = n_e - 1;
  if (r1 >= n_e) r1 = n_e - 1;
  const bf16_t* ga0 = xb + (size_t)bucket_tok[off + r0] * HD + kch;
  const bf16_t* ga1 = xb + (size_t)bucket_tok[off + r1] * HD + kch;
  const bf16_t* gb0 = W1T + ((size_t)e * ID + n_base + w * 32 + srow) * HD + kch;
  const bf16_t* gb1 = gb0 + (size_t)16 * HD;
  const int laofs0 = w * 1024 + lane * 8;  // rows w*32.. in [128][32]
  const int laofs1 = laofs0 + 512;         // +16 rows

  f32x4 acc[4][4];
#pragma unroll
  for (int mt = 0; mt < 4; ++mt)
#pragma unroll
    for (int nt = 0; nt < 4; ++nt)
#pragma unroll
      for (int r = 0; r < 4; ++r) acc[mt][nt][r] = 0.f;

  // prologue: stage tiles 0 and 1 (8 outstanding GLOADs/wave)
#pragma unroll
  for (int p = 0; p < 2; ++p) {
    const size_t ko = (size_t)p * 32;
    GLOAD(ga0 + ko, &As[p][laofs0]);
    GLOAD(ga1 + ko, &As[p][laofs1]);
    GLOAD(gb0 + ko, &Bs[p][laofs0]);
    GLOAD(gb1 + ko, &Bs[p][laofs1]);
  }

#define NT1 (HD / 32)
  for (int kt = 0; kt < NT1; ++kt) {
    WAITL0();                          // prior iter's ds_reads done (per-wave)
    __builtin_amdgcn_s_barrier();      // #1: buf[(kt+2)%3] free to overwrite
    if (kt + 2 < NT1) {
      const int nxt = (kt + 2) % 3;
      const size_t ko = (size_t)(kt + 2) * 32;
      GLOAD(ga0 + ko, &As[nxt][laofs0]);
      GLOAD(ga1 + ko, &As[nxt][laofs1]);
      GLOAD(gb0 + ko, &Bs[nxt][laofs0]);
      GLOAD(gb1 + ko, &Bs[nxt][laofs1]);
      WAITV(8);                        // tile kt landed; kt+1,kt+2 in flight
    } else if (kt + 1 < NT1) {
      WAITV(4);
    } else {
      WAITV(0);
    }
    __builtin_amdgcn_s_barrier();      // #2: tile kt visible to all waves
    __builtin_amdgcn_sched_barrier(0); // fence: no ds_read hoists above
    const int cur = kt % 3;
    const int slot = (quad ^ (lrow & 3)) * 8;
    bf16x8 af[4], bfr[4];
#pragma unroll
    for (int i = 0; i < 4; ++i) {
      af[i] = *(const bf16x8*)(&As[cur][(wm * 64 + i * 16 + lrow) * 32 + slot]);
      bfr[i] = *(const bf16x8*)(&Bs[cur][(wn * 64 + i * 16 + lrow) * 32 + slot]);
    }
#pragma unroll
    for (int mt = 0; mt < 4; ++mt)
#pragma unroll
      for (int nt = 0; nt < 4; ++nt)
        acc[mt][nt] =
            __builtin_amdgcn_mfma_f32_16x16x32_bf16(af[mt], bfr[nt], acc[mt][nt], 0, 0, 0);
  }

#pragma unroll
  for (int mt = 0; mt < 4; ++mt) {
#pragma unroll
    for (int r = 0; r < 4; ++r) {
      const int gm = m_base + wm * 64 + mt * 16 + quad * 4 + r;
      if (gm < n_e) {
        bf16_t* orow = h1 + (size_t)(off + gm) * ID;
#pragma unroll
        for (int nt = 0; nt < 4; ++nt) {
          const int gi = n_base + wn * 64 + nt * 16 + lrow;
          float v = acc[mt][nt][r] + b1[e * ID + gi];
          v = 0.5f * v * (1.f + erff(v * 0.70710678118654752f));  // exact-erf GELU
          orow[gi] = (bf16_t)v;
        }
      }
    }
  }
}

__global__ __launch_bounds__(256, 3) void gemm2_kernel(
    const bf16_t* __restrict__ h1, const bf16_t* __restrict__ W2T, const float* __restrict__ b2,
    const int* __restrict__ counts, const int* __restrict__ offsets,
    const int* __restrict__ bucket_tok, const float* __restrict__ bucket_w,
    const int* __restrict__ wl_e, const int* __restrict__ wl_m, const int* __restrict__ n_work,
    float* __restrict__ out) {
  const int widx = blockIdx.x;
  if (widx >= *n_work) return;
  const int e = wl_e[widx];
  const int m_base = wl_m[widx];
  const int n_e = counts[e];
  const int n_base = blockIdx.y * 128;
  const int off = offsets[e];

  __shared__ bf16_t As[3][128 * 32];
  __shared__ bf16_t Bs[3][128 * 32];

  const int tid = threadIdx.x;
  const int w = tid >> 6;
  const int lane = tid & 63;
  const int quad = lane >> 4;
  const int lrow = lane & 15;
  const int wm = w >> 1;
  const int wn = w & 1;

  const int srow = lane >> 2;
  const int kch = (((lane & 3) ^ (srow & 3)) * 8);
  int r0 = m_base + w * 32 + srow;
  int r1 = r0 + 16;
  if (r0 >= n_e) r0 = n_e - 1;
  if (r1 >= n_e) r1 = n_e - 1;
  const bf16_t* ga0 = h1 + (size_t)(off + r0) * ID + kch;
  const bf16_t* ga1 = h1 + (size_t)(off + r1) * ID + kch;
  const bf16_t* gb0 = W2T + ((size_t)e * HD + n_base + w * 32 + srow) * ID + kch;
  const bf16_t* gb1 = gb0 + (size_t)16 * ID;
  const int laofs0 = w * 1024 + lane * 8;
  const int laofs1 = laofs0 + 512;

  f32x4 acc[4][4];
#pragma unroll
  for (int mt = 0; mt < 4; ++mt)
#pragma unroll
    for (int nt = 0; nt < 4; ++nt)
#pragma unroll
      for (int r = 0; r < 4; ++r) acc[mt][nt][r] = 0.f;

#pragma unroll
  for (int p = 0; p < 2; ++p) {
    const size_t ko = (size_t)p * 32;
    GLOAD(ga0 + ko, &As[p][laofs0]);
    GLOAD(ga1 + ko, &As[p][laofs1]);
    GLOAD(gb0 + ko, &Bs[p][laofs0]);
    GLOAD(gb1 + ko, &Bs[p][laofs1]);
  }

#define NT2 (ID / 32)
  for (int kt = 0; kt < NT2; ++kt) {
    WAITL0();
    __builtin_amdgcn_s_barrier();
    if (kt + 2 < NT2) {
      const int nxt = (kt + 2) % 3;
      const size_t ko = (size_t)(kt + 2) * 32;
      GLOAD(ga0 + ko, &As[nxt][laofs0]);
      GLOAD(ga1 + ko, &As[nxt][laofs1]);
      GLOAD(gb0 + ko, &Bs[nxt][laofs0]);
      GLOAD(gb1 + ko, &Bs[nxt][laofs1]);
      WAITV(8);
    } else if (kt + 1 < NT2) {
      WAITV(4);
    } else {
      WAITV(0);
    }
    __builtin_amdgcn_s_barrier();
    __builtin_amdgcn_sched_barrier(0);
    const int cur = kt % 3;
    const int slot = (quad ^ (lrow & 3)) * 8;
    bf16x8 af[4], bfr[4];
#pragma unroll
    for (int i = 0; i < 4; ++i) {
      af[i] = *(const bf16x8*)(&As[cur][(wm * 64 + i * 16 + lrow) * 32 + slot]);
      bfr[i] = *(const bf16x8*)(&Bs[cur][(wn * 64 + i * 16 + lrow) * 32 + slot]);
    }
#pragma unroll
    for (int mt = 0; mt < 4; ++mt)
#pragma unroll
      for (int nt = 0; nt < 4; ++nt)
        acc[mt][nt] =
            __builtin_amdgcn_mfma_f32_16x16x32_bf16(af[mt], bfr[nt], acc[mt][nt], 0, 0, 0);
  }

#pragma unroll
  for (int mt = 0; mt < 4; ++mt) {
#pragma unroll
    for (int r = 0; r < 4; ++r) {
      const int gm = m_base + wm * 64 + mt * 16 + quad * 4 + r;
      if (gm < n_e) {
        const int pos = off + gm;
        const int tokid = bucket_tok[pos];
        const float wgt = bucket_w[pos];
        float* orow = out + (size_t)tokid * HD;
#pragma unroll
        for (int nt = 0; nt < 4; ++nt) {
          const int gh = n_base + wn * 64 + nt * 16 + lrow;
          float v = acc[mt][nt][r] + b2[e * HD + gh];
          atomicAdd(orow + gh, wgt * v);
        }
      }
    }
  }
}

extern "C" void kernel_launch(void* const* d_in, const int* in_sizes, int n_in,
                              void* d_out, int out_size, void* d_ws, size_t ws_size,
                              hipStream_t stream) {
  const float* x = (const float*)d_in[0];
  const float* Wg = (const float*)d_in[1];
  const float* W1 = (const float*)d_in[2];
  const float* b1 = (const float*)d_in[3];
  const float* W2 = (const float*)d_in[4];
  const float* b2 = (const float*)d_in[5];
  float* out = (float*)d_out;
  char* ws = (char*)d_ws;

  int* counts = (int*)(ws + WS_COUNTS);
  int* offsets = (int*)(ws + WS_OFFSETS);
  int* bucket_tok = (int*)(ws + WS_BTOK);
  float* bucket_w = (float*)(ws + WS_BW);
  int* tok_e = (int*)(ws + WS_TE);
  float* tok_w = (float*)(ws + WS_TW);
  int* wl_e = (int*)(ws + WS_WL);
  int* wl_m = wl_e + MAXWL;
  int* n_work = wl_m + MAXWL;
  int* blk_cnt = (int*)(ws + WS_BLKC);
  int* blk_base = (int*)(ws + WS_BLKB);
  bf16_t* xb = (bf16_t*)(ws + WS_XB);
  bf16_t* h1 = (bf16_t*)(ws + WS_H1);
  bf16_t* WT = (bf16_t*)(ws + WS_WT);

  zero_kernel<<<(TOKS * HD / 4) / 256, 256, 0, stream>>>(out);
  convert_kernel<<<TOKS * HD / (256 * 8), 256, 0, stream>>>(x, xb);
  gate_kernel<<<TOKS / 8, 256, 0, stream>>>(x, Wg, tok_e, tok_w);
  hist_kernel<<<TOKS * 2 / 256, 256, 0, stream>>>(tok_e, blk_cnt);
  scan_kernel<<<1, 64, 0, stream>>>(blk_cnt, counts, offsets, blk_base, wl_e, wl_m, n_work);
  scatter_kernel<<<TOKS * 2 / 256, 256, 0, stream>>>(tok_e, tok_w, blk_base, bucket_tok,
                                                     bucket_w);
  transpose_convert_kernel<<<dim3(HD / 64, ID / 64, NE), 256, 0, stream>>>(W1, WT, HD, ID);
  gemm1_kernel<<<dim3(MAXWL, ID / 128), 256, 0, stream>>>(xb, WT, b1, counts, offsets, bucket_tok,
                                                          wl_e, wl_m, n_work, h1);
  transpose_convert_kernel<<<dim3(ID / 64, HD / 64, NE), 256, 0, stream>>>(W2, WT, ID, HD);
  gemm2_kernel<<<dim3(MAXWL, HD / 128), 256, 0, stream>>>(h1, WT, b2, counts, offsets,
                                                          bucket_tok, bucket_w, wl_e, wl_m,
                                                          n_work, out);
}